// Round 1
// baseline (6502.012 us; speedup 1.0000x reference)
//
#include <hip/hip_runtime.h>
#include <math.h>

#define B_  2048
#define S_  32
#define T_  32
#define D_  128
#define H_  256
#define G3  768   // 3*H
#define VT_ 256

struct Leg {
  const float* A;
  const float* Bw;
  const float* bias;
  float*       C;
  const int*   rowIdx;
  int idxStride;
  int N, K, lda, ldb, ldc;
};

#define BM 64
#define BN 64
#define BK 32

__global__ __launch_bounds__(256)
void gemm_legs(Leg l0, Leg l1, Leg l2, Leg l3) {
  Leg L = (blockIdx.z == 0) ? l0 : (blockIdx.z == 1) ? l1 : (blockIdx.z == 2) ? l2 : l3;
  int n0 = blockIdx.x * BN;
  if (n0 >= L.N) return;
  int m0 = blockIdx.y * BM;
  __shared__ float As[BK][BM + 1];
  __shared__ float Bs[BK][BN];
  int tid = threadIdx.x;
  int ka = tid & 31, ra = tid >> 5;   // A-load: col k, row group
  int nn = tid & 63, kb = tid >> 6;   // B-load
  int tx = tid & 15, ty = tid >> 4;   // compute microtile
  float acc[4][4] = {};
  for (int k0 = 0; k0 < L.K; k0 += BK) {
    #pragma unroll
    for (int i = 0; i < 8; i++) {
      int m = m0 + ra + i * 8;
      int arow = L.rowIdx ? L.rowIdx[(size_t)m * L.idxStride] : m;
      As[ka][ra + i * 8] = L.A[(size_t)arow * L.lda + k0 + ka];
    }
    #pragma unroll
    for (int i = 0; i < 8; i++) {
      Bs[kb + i * 4][nn] = L.Bw[(size_t)(k0 + kb + i * 4) * L.ldb + n0 + nn];
    }
    __syncthreads();
    #pragma unroll
    for (int kk = 0; kk < BK; kk++) {
      float a[4], b[4];
      #pragma unroll
      for (int i = 0; i < 4; i++) a[i] = As[kk][ty * 4 + i];
      #pragma unroll
      for (int j = 0; j < 4; j++) b[j] = Bs[kk][tx * 4 + j];
      #pragma unroll
      for (int i = 0; i < 4; i++)
        #pragma unroll
        for (int j = 0; j < 4; j++) acc[i][j] = fmaf(a[i], b[j], acc[i][j]);
    }
    __syncthreads();
  }
  #pragma unroll
  for (int i = 0; i < 4; i++) {
    int m = m0 + ty * 4 + i;
    #pragma unroll
    for (int j = 0; j < 4; j++) {
      int n = n0 + tx * 4 + j;
      float v = acc[i][j];
      if (L.bias) v += L.bias[n];
      L.C[(size_t)m * L.ldc + n] = v;
    }
  }
}

__device__ inline float sigm(float x) { return 1.f / (1.f + expf(-x)); }

// dir 0: forward (writes pos s), dir 1: backward (writes pos S-1-s)
__global__ __launch_bounds__(256)
void enc_gate(const float* __restrict__ gxf, const float* __restrict__ ghf,
              const float* __restrict__ gxb, const float* __restrict__ ghb,
              float* __restrict__ hf, float* __restrict__ hb,
              float* __restrict__ ss, int s) {
  int idx = blockIdx.x * 256 + threadIdx.x;          // over B*H
  int dir = blockIdx.y;
  const float* gx = dir ? gxb : gxf;
  const float* gh = dir ? ghb : ghf;
  float* h = dir ? hb : hf;
  int b = idx >> 8, j = idx & 255;
  size_t g = (size_t)b * G3 + j;
  float z = sigm(gx[g] + gh[g]);
  float r = sigm(gx[g + H_] + gh[g + H_]);
  float c = tanhf(gx[g + 2 * H_] + r * gh[g + 2 * H_]);
  float hn = z * h[idx] + (1.f - z) * c;
  h[idx] = hn;
  int pos = dir ? (S_ - 1 - s) : s;
  ss[((size_t)pos * B_ + b) * H_ + j] += hn;
}

__global__ __launch_bounds__(256)
void dec_gate(const float* __restrict__ gx, const float* __restrict__ gc,
              const float* __restrict__ gh,
              const float* __restrict__ h_in, float* __restrict__ h_out) {
  int idx = blockIdx.x * 256 + threadIdx.x;
  int b = idx >> 8, j = idx & 255;
  size_t g = (size_t)b * G3 + j;
  float xz = gx[g] + gc[g];
  float xr = gx[g + H_] + gc[g + H_];
  float xh = gx[g + 2 * H_] + gc[g + 2 * H_];
  float z = sigm(xz + gh[g]);
  float r = sigm(xr + gh[g + H_]);
  float c = tanhf(xh + r * gh[g + 2 * H_]);
  h_out[idx] = z * h_in[idx] + (1.f - z) * c;
}

// one block per batch row b; 256 threads
__global__ __launch_bounds__(256)
void attend_k(const float* __restrict__ proj, const float* __restrict__ ss,
              const float* __restrict__ p, const float* __restrict__ att_v,
              float* __restrict__ ctx) {
  int b = blockIdx.x;
  int tid = threadIdx.x;
  int lane = tid & 63;
  int wv = tid >> 6;            // 4 waves, each handles 8 source positions
  __shared__ float e_s[S_];
  __shared__ float w_s[S_];
  float pq[4], vq[4];
  #pragma unroll
  for (int q = 0; q < 4; q++) {
    pq[q] = p[(size_t)b * H_ + q * 64 + lane];
    vq[q] = att_v[q * 64 + lane];
  }
  #pragma unroll
  for (int i = 0; i < 8; i++) {
    int s = wv * 8 + i;
    const float* pr = proj + ((size_t)s * B_ + b) * H_;
    float part = 0.f;
    #pragma unroll
    for (int q = 0; q < 4; q++)
      part += tanhf(pr[q * 64 + lane] + pq[q]) * vq[q];
    #pragma unroll
    for (int off = 32; off; off >>= 1)
      part += __shfl_xor(part, off);
    if (lane == 0) e_s[s] = part;
  }
  __syncthreads();
  float m = -1e30f;
  #pragma unroll
  for (int s = 0; s < S_; s++) m = fmaxf(m, e_s[s]);
  float den = 0.f;
  #pragma unroll
  for (int s = 0; s < S_; s++) den += expf(e_s[s] - m);
  if (tid < S_) w_s[tid] = expf(e_s[tid] - m) / den;
  __syncthreads();
  float acc = 0.f;
  #pragma unroll
  for (int s = 0; s < S_; s++)
    acc = fmaf(w_s[s], ss[((size_t)s * B_ + b) * H_ + tid], acc);
  ctx[(size_t)b * H_ + tid] = acc;
}

extern "C" void kernel_launch(void* const* d_in, const int* in_sizes, int n_in,
                              void* d_out, int out_size, void* d_ws, size_t ws_size,
                              hipStream_t stream) {
  const float* src_emb   = (const float*)d_in[0];
  const float* tgt_emb   = (const float*)d_in[1];
  const float* enc_f_W   = (const float*)d_in[2];
  const float* enc_f_U   = (const float*)d_in[3];
  const float* enc_f_b   = (const float*)d_in[4];
  const float* enc_b_W   = (const float*)d_in[5];
  const float* enc_b_U   = (const float*)d_in[6];
  const float* enc_b_b   = (const float*)d_in[7];
  const float* dec_W     = (const float*)d_in[8];
  const float* dec_U     = (const float*)d_in[9];
  const float* dec_b     = (const float*)d_in[10];
  const float* out_W     = (const float*)d_in[11];
  const float* out_b     = (const float*)d_in[12];
  const float* att_src_W = (const float*)d_in[13];
  const float* att_src_b = (const float*)d_in[14];
  const float* att_st_W  = (const float*)d_in[15];
  const float* att_st_b  = (const float*)d_in[16];
  const float* att_v     = (const float*)d_in[17];
  // d_in[18] = att_v_b: softmax shift-invariant -> unused
  const int* source_ids  = (const int*)d_in[19];
  const int* target_ids  = (const int*)d_in[20];
  float* out = (float*)d_out;

  float* w = (float*)d_ws;
  size_t off = 0;
  auto alloc = [&](size_t n) { float* p = w + off; off += n; return p; };
  float* ss   = alloc((size_t)S_ * B_ * H_);   // source_states (S,B,H)
  float* proj = alloc((size_t)S_ * B_ * H_);   // proj_src (S,B,H)
  float* hf   = alloc((size_t)B_ * H_);
  float* hb   = alloc((size_t)B_ * H_);
  float* g0   = alloc((size_t)B_ * G3);        // gx_f  / GX_emb
  float* g1   = alloc((size_t)B_ * G3);        // gh_f  / GH
  float* g2   = alloc((size_t)B_ * G3);        // gx_b  / GC
  float* g3   = alloc((size_t)B_ * G3);        // gh_b
  float* hdec = alloc((size_t)B_ * H_);
  float* ctx  = alloc((size_t)B_ * H_);
  float* pbuf = alloc((size_t)B_ * H_);

  hipMemsetAsync(ss, 0, (size_t)S_ * B_ * H_ * sizeof(float), stream);
  hipMemsetAsync(hf, 0, (size_t)B_ * H_ * sizeof(float), stream);
  hipMemsetAsync(hb, 0, (size_t)B_ * H_ * sizeof(float), stream);

  Leg Z = {};

  // ---------- encoder ----------
  for (int s = 0; s < S_; s++) {
    Leg gxf = { src_emb, enc_f_W, enc_f_b,      g0, source_ids + s,            S_, G3, D_, D_, G3, G3 };
    Leg ghf = { hf,      enc_f_U, enc_f_b + G3, g1, nullptr,                   0,  G3, H_, H_, G3, G3 };
    Leg gxb = { src_emb, enc_b_W, enc_b_b,      g2, source_ids + (S_ - 1 - s), S_, G3, D_, D_, G3, G3 };
    Leg ghb = { hb,      enc_b_U, enc_b_b + G3, g3, nullptr,                   0,  G3, H_, H_, G3, G3 };
    gemm_legs<<<dim3(G3 / BN, B_ / BM, 4), 256, 0, stream>>>(gxf, ghf, gxb, ghb);
    enc_gate<<<dim3((B_ * H_) / 256, 2), 256, 0, stream>>>(g0, g1, g2, g3, hf, hb, ss, s);
  }

  // ---------- proj_src = ss @ att_src_W + b ----------
  {
    Leg pr = { ss, att_src_W, att_src_b, proj, nullptr, 0, H_, H_, H_, H_, H_ };
    gemm_legs<<<dim3(H_ / BN, (S_ * B_) / BM, 1), 256, 0, stream>>>(pr, Z, Z, Z);
  }

  // ---------- initial attention with h0 = ss[:,0] ----------
  {
    Leg p0 = { ss, att_st_W, att_st_b, pbuf, nullptr, 0, H_, H_, H_, H_, H_ };
    gemm_legs<<<dim3(H_ / BN, B_ / BM, 1), 256, 0, stream>>>(p0, Z, Z, Z);
    attend_k<<<B_, 256, 0, stream>>>(proj, ss, pbuf, att_v, ctx);
  }

  // ---------- decoder ----------
  for (int t = 0; t < T_; t++) {
    const float* hprev = (t == 0) ? ss : hdec;  // ss[0] == h0 (first B*H block)
    Leg GH = { hprev, dec_U, dec_b + G3, g1, nullptr, 0, G3, H_, H_, G3, G3 };
    Leg GC = { ctx, dec_W + (size_t)D_ * G3, nullptr, g2, nullptr, 0, G3, H_, H_, G3, G3 };
    Leg GX;
    if (t == 0) {
      GX = { tgt_emb + 1 * D_ /*BOW=1*/, dec_W, dec_b, g0, nullptr, 0, G3, D_, 0, G3, G3 };
    } else {
      GX = { tgt_emb, dec_W, dec_b, g0, target_ids + (t - 1), T_, G3, D_, D_, G3, G3 };
    }
    gemm_legs<<<dim3(G3 / BN, B_ / BM, 3), 256, 0, stream>>>(GH, GC, GX, Z);
    dec_gate<<<(B_ * H_) / 256, 256, 0, stream>>>(g0, g2, g1, hprev, hdec);

    Leg LO = { hdec, out_W, out_b, out + (size_t)t * VT_, nullptr, 0, VT_, H_, H_, VT_, T_ * VT_ };
    Leg LP = { hdec, att_st_W, att_st_b, pbuf, nullptr, 0, H_, H_, H_, H_, H_ };
    gemm_legs<<<dim3(G3 / BN, B_ / BM, 2), 256, 0, stream>>>(LO, LP, Z, Z);

    if (t < T_ - 1)
      attend_k<<<B_, 256, 0, stream>>>(proj, ss, pbuf, att_v, ctx);
  }
}

// Round 2
// 3865.682 us; speedup vs baseline: 1.6820x; 1.6820x over previous
//
#include <hip/hip_runtime.h>
#include <math.h>

#define B_  2048
#define S_  32
#define T_  32
#define D_  128
#define H_  256
#define G3  768   // 3*H
#define VT_ 256

typedef __attribute__((ext_vector_type(8))) short short8;
typedef __attribute__((ext_vector_type(4))) float f32x4;
typedef __attribute__((ext_vector_type(4))) unsigned short us4;
typedef __attribute__((ext_vector_type(8))) unsigned short us8;

__device__ inline unsigned short f2bf(float x) {
  union { float f; unsigned u; } v; v.f = x;
  unsigned r = v.u + 0x7FFFu + ((v.u >> 16) & 1u);   // RN-even
  return (unsigned short)(r >> 16);
}
__device__ inline float bf2f(unsigned short b) {
  union { unsigned u; float f; } v; v.u = ((unsigned)b) << 16;
  return v.f;
}

struct Leg {
  const float* A;
  const float* Bw;
  const float* bias;
  float*       C;
  const int*   rowIdx;
  int idxStride;
  int N, K, lda, ldb, ldc;
};

#define BM 128
#define BN 128
#define BK 32

// swizzle: ushort-index XOR, bits 3-5, bijective for stride-1 and stride-8 rows
__device__ inline int swz(int row) { return ((row ^ (row >> 3)) & 7) << 3; }

__global__ __launch_bounds__(256)
void gemm_legs(Leg l0, Leg l1, Leg l2, Leg l3) {
  Leg L = (blockIdx.z == 0) ? l0 : (blockIdx.z == 1) ? l1 : (blockIdx.z == 2) ? l2 : l3;
  int n0 = blockIdx.x * BN;
  if (n0 >= L.N) return;
  int m0 = blockIdx.y * BM;

  // row = 64 ushorts: [0..31]=hi(k), [32..63]=lo(k); 128B rows, XOR-swizzled
  __shared__ unsigned short As[BM * 64];
  __shared__ unsigned short Bs[BN * 64];

  int tid = threadIdx.x;
  // A staging: thread loads float4 at (a_row + 32i, a_k4)
  int a_row = tid >> 3;            // 0..31
  int a_k4  = (tid & 7) * 4;       // 0..28
  // B staging: thread loads 16 k's for one n
  int b_n = tid & 127;             // 0..127
  int b_h = tid >> 7;              // 0..1

  // wave fragment mapping
  int lane = tid & 63;
  int wv = tid >> 6;
  int wr = (wv >> 1) * 64;
  int wc = (wv & 1) * 64;
  int fr = lane & 15;              // frag row (A) / col (B)
  int fk = (lane >> 4) * 8;        // frag k offset

  f32x4 acc[4][4];
  #pragma unroll
  for (int m = 0; m < 4; m++)
    #pragma unroll
    for (int n = 0; n < 4; n++)
      acc[m][n] = (f32x4){0.f, 0.f, 0.f, 0.f};

  size_t a_base[4];
  #pragma unroll
  for (int i = 0; i < 4; i++) {
    int m = m0 + a_row + 32 * i;
    int ar = L.rowIdx ? L.rowIdx[(size_t)m * L.idxStride] : m;
    a_base[i] = (size_t)ar * L.lda;
  }

  for (int k0 = 0; k0 < L.K; k0 += BK) {
    // ---- global loads (issued before barrier: overlap prev MFMA) ----
    f32x4 av[4];
    #pragma unroll
    for (int i = 0; i < 4; i++)
      av[i] = *(const f32x4*)(L.A + a_base[i] + k0 + a_k4);
    float bv[16];
    #pragma unroll
    for (int kk = 0; kk < 16; kk++)
      bv[kk] = L.Bw[(size_t)(k0 + b_h * 16 + kk) * L.ldb + n0 + b_n];

    if (k0) __syncthreads();   // prev frag reads done before overwrite

    // ---- A -> LDS (hi/lo split) ----
    #pragma unroll
    for (int i = 0; i < 4; i++) {
      int r = a_row + 32 * i;
      int sw = swz(r);
      us4 hv, lv;
      #pragma unroll
      for (int j = 0; j < 4; j++) {
        float x = av[i][j];
        unsigned short h = f2bf(x);
        hv[j] = h;
        lv[j] = f2bf(x - bf2f(h));
      }
      *(us4*)&As[(r * 64 + a_k4) ^ sw]      = hv;
      *(us4*)&As[(r * 64 + 32 + a_k4) ^ sw] = lv;
    }
    // ---- B^T -> LDS (hi/lo split) ----
    {
      int r = b_n;
      int sw = swz(r);
      us8 h0, h1, l0v, l1v;
      #pragma unroll
      for (int kk = 0; kk < 8; kk++) {
        unsigned short h = f2bf(bv[kk]);
        h0[kk] = h; l0v[kk] = f2bf(bv[kk] - bf2f(h));
        unsigned short h2 = f2bf(bv[kk + 8]);
        h1[kk] = h2; l1v[kk] = f2bf(bv[kk + 8] - bf2f(h2));
      }
      int kbase = b_h * 16;
      *(us8*)&Bs[(r * 64 + kbase) ^ sw]          = h0;
      *(us8*)&Bs[(r * 64 + kbase + 8) ^ sw]      = h1;
      *(us8*)&Bs[(r * 64 + 32 + kbase) ^ sw]     = l0v;
      *(us8*)&Bs[(r * 64 + 32 + kbase + 8) ^ sw] = l1v;
    }
    __syncthreads();

    // ---- fragments + 3-pass MFMA ----
    short8 bhi[4], blo[4];
    #pragma unroll
    for (int n = 0; n < 4; n++) {
      int r = wc + n * 16 + fr;
      int sw = swz(r);
      bhi[n] = *(const short8*)&Bs[(r * 64 + fk) ^ sw];
      blo[n] = *(const short8*)&Bs[(r * 64 + 32 + fk) ^ sw];
    }
    #pragma unroll
    for (int m = 0; m < 4; m++) {
      int r = wr + m * 16 + fr;
      int sw = swz(r);
      short8 ahi = *(const short8*)&As[(r * 64 + fk) ^ sw];
      short8 alo = *(const short8*)&As[(r * 64 + 32 + fk) ^ sw];
      #pragma unroll
      for (int n = 0; n < 4; n++) {
        acc[m][n] = __builtin_amdgcn_mfma_f32_16x16x32_bf16(ahi, bhi[n], acc[m][n], 0, 0, 0);
        acc[m][n] = __builtin_amdgcn_mfma_f32_16x16x32_bf16(ahi, blo[n], acc[m][n], 0, 0, 0);
        acc[m][n] = __builtin_amdgcn_mfma_f32_16x16x32_bf16(alo, bhi[n], acc[m][n], 0, 0, 0);
      }
    }
  }

  // ---- epilogue: C/D layout col=lane&15, row=(lane>>4)*4+reg ----
  int rbase = (lane >> 4) * 4;
  #pragma unroll
  for (int m = 0; m < 4; m++) {
    #pragma unroll
    for (int rr = 0; rr < 4; rr++) {
      int row = m0 + wr + m * 16 + rbase + rr;
      #pragma unroll
      for (int n = 0; n < 4; n++) {
        int col = n0 + wc + n * 16 + fr;
        float v = acc[m][n][rr];
        if (L.bias) v += L.bias[col];
        L.C[(size_t)row * L.ldc + col] = v;
      }
    }
  }
}

__device__ inline float sigm(float x) { return 1.f / (1.f + expf(-x)); }

__global__ __launch_bounds__(256)
void enc_gate(const float* __restrict__ gxf, const float* __restrict__ ghf,
              const float* __restrict__ gxb, const float* __restrict__ ghb,
              float* __restrict__ hf, float* __restrict__ hb,
              float* __restrict__ ss, int s) {
  int idx = blockIdx.x * 256 + threadIdx.x;
  int dir = blockIdx.y;
  const float* gx = dir ? gxb : gxf;
  const float* gh = dir ? ghb : ghf;
  float* h = dir ? hb : hf;
  int b = idx >> 8, j = idx & 255;
  size_t g = (size_t)b * G3 + j;
  float z = sigm(gx[g] + gh[g]);
  float r = sigm(gx[g + H_] + gh[g + H_]);
  float c = tanhf(gx[g + 2 * H_] + r * gh[g + 2 * H_]);
  float hn = z * h[idx] + (1.f - z) * c;
  h[idx] = hn;
  int pos = dir ? (S_ - 1 - s) : s;
  ss[((size_t)pos * B_ + b) * H_ + j] += hn;
}

__global__ __launch_bounds__(256)
void dec_gate(const float* __restrict__ gx, const float* __restrict__ gc,
              const float* __restrict__ gh,
              const float* __restrict__ h_in, float* __restrict__ h_out) {
  int idx = blockIdx.x * 256 + threadIdx.x;
  int b = idx >> 8, j = idx & 255;
  size_t g = (size_t)b * G3 + j;
  float xz = gx[g] + gc[g];
  float xr = gx[g + H_] + gc[g + H_];
  float xh = gx[g + 2 * H_] + gc[g + 2 * H_];
  float z = sigm(xz + gh[g]);
  float r = sigm(xr + gh[g + H_]);
  float c = tanhf(xh + r * gh[g + 2 * H_]);
  h_out[idx] = z * h_in[idx] + (1.f - z) * c;
}

__global__ __launch_bounds__(256)
void attend_k(const float* __restrict__ proj, const float* __restrict__ ss,
              const float* __restrict__ p, const float* __restrict__ att_v,
              float* __restrict__ ctx) {
  int b = blockIdx.x;
  int tid = threadIdx.x;
  int lane = tid & 63;
  int wv = tid >> 6;
  __shared__ float e_s[S_];
  __shared__ float w_s[S_];
  float pq[4], vq[4];
  #pragma unroll
  for (int q = 0; q < 4; q++) {
    pq[q] = p[(size_t)b * H_ + q * 64 + lane];
    vq[q] = att_v[q * 64 + lane];
  }
  #pragma unroll
  for (int i = 0; i < 8; i++) {
    int s = wv * 8 + i;
    const float* pr = proj + ((size_t)s * B_ + b) * H_;
    float part = 0.f;
    #pragma unroll
    for (int q = 0; q < 4; q++)
      part += tanhf(pr[q * 64 + lane] + pq[q]) * vq[q];
    #pragma unroll
    for (int off = 32; off; off >>= 1)
      part += __shfl_xor(part, off);
    if (lane == 0) e_s[s] = part;
  }
  __syncthreads();
  float m = -1e30f;
  #pragma unroll
  for (int s = 0; s < S_; s++) m = fmaxf(m, e_s[s]);
  float den = 0.f;
  #pragma unroll
  for (int s = 0; s < S_; s++) den += expf(e_s[s] - m);
  if (tid < S_) w_s[tid] = expf(e_s[tid] - m) / den;
  __syncthreads();
  float acc = 0.f;
  #pragma unroll
  for (int s = 0; s < S_; s++)
    acc = fmaf(w_s[s], ss[((size_t)s * B_ + b) * H_ + tid], acc);
  ctx[(size_t)b * H_ + tid] = acc;
}

extern "C" void kernel_launch(void* const* d_in, const int* in_sizes, int n_in,
                              void* d_out, int out_size, void* d_ws, size_t ws_size,
                              hipStream_t stream) {
  const float* src_emb   = (const float*)d_in[0];
  const float* tgt_emb   = (const float*)d_in[1];
  const float* enc_f_W   = (const float*)d_in[2];
  const float* enc_f_U   = (const float*)d_in[3];
  const float* enc_f_b   = (const float*)d_in[4];
  const float* enc_b_W   = (const float*)d_in[5];
  const float* enc_b_U   = (const float*)d_in[6];
  const float* enc_b_b   = (const float*)d_in[7];
  const float* dec_W     = (const float*)d_in[8];
  const float* dec_U     = (const float*)d_in[9];
  const float* dec_b     = (const float*)d_in[10];
  const float* out_W     = (const float*)d_in[11];
  const float* out_b     = (const float*)d_in[12];
  const float* att_src_W = (const float*)d_in[13];
  const float* att_src_b = (const float*)d_in[14];
  const float* att_st_W  = (const float*)d_in[15];
  const float* att_st_b  = (const float*)d_in[16];
  const float* att_v     = (const float*)d_in[17];
  const int* source_ids  = (const int*)d_in[19];
  const int* target_ids  = (const int*)d_in[20];
  float* out = (float*)d_out;

  float* w = (float*)d_ws;
  size_t off = 0;
  auto alloc = [&](size_t n) { float* p = w + off; off += n; return p; };
  float* ss   = alloc((size_t)S_ * B_ * H_);
  float* proj = alloc((size_t)S_ * B_ * H_);
  float* hf   = alloc((size_t)B_ * H_);
  float* hb   = alloc((size_t)B_ * H_);
  float* g0   = alloc((size_t)B_ * G3);
  float* g1   = alloc((size_t)B_ * G3);
  float* g2   = alloc((size_t)B_ * G3);
  float* g3   = alloc((size_t)B_ * G3);
  float* hdec = alloc((size_t)B_ * H_);
  float* ctx  = alloc((size_t)B_ * H_);
  float* pbuf = alloc((size_t)B_ * H_);

  hipMemsetAsync(ss, 0, (size_t)S_ * B_ * H_ * sizeof(float), stream);
  hipMemsetAsync(hf, 0, (size_t)B_ * H_ * sizeof(float), stream);
  hipMemsetAsync(hb, 0, (size_t)B_ * H_ * sizeof(float), stream);

  Leg Z = {};

  // ---------- encoder ----------
  for (int s = 0; s < S_; s++) {
    Leg gxf = { src_emb, enc_f_W, enc_f_b,      g0, source_ids + s,            S_, G3, D_, D_, G3, G3 };
    Leg ghf = { hf,      enc_f_U, enc_f_b + G3, g1, nullptr,                   0,  G3, H_, H_, G3, G3 };
    Leg gxb = { src_emb, enc_b_W, enc_b_b,      g2, source_ids + (S_ - 1 - s), S_, G3, D_, D_, G3, G3 };
    Leg ghb = { hb,      enc_b_U, enc_b_b + G3, g3, nullptr,                   0,  G3, H_, H_, G3, G3 };
    gemm_legs<<<dim3(G3 / BN, B_ / BM, 4), 256, 0, stream>>>(gxf, ghf, gxb, ghb);
    enc_gate<<<dim3((B_ * H_) / 256, 2), 256, 0, stream>>>(g0, g1, g2, g3, hf, hb, ss, s);
  }

  // ---------- proj_src ----------
  {
    Leg pr = { ss, att_src_W, att_src_b, proj, nullptr, 0, H_, H_, H_, H_, H_ };
    gemm_legs<<<dim3(H_ / BN, (S_ * B_) / BM, 1), 256, 0, stream>>>(pr, Z, Z, Z);
  }

  // ---------- initial attention ----------
  {
    Leg p0 = { ss, att_st_W, att_st_b, pbuf, nullptr, 0, H_, H_, H_, H_, H_ };
    gemm_legs<<<dim3(H_ / BN, B_ / BM, 1), 256, 0, stream>>>(p0, Z, Z, Z);
    attend_k<<<B_, 256, 0, stream>>>(proj, ss, pbuf, att_v, ctx);
  }

  // ---------- decoder ----------
  for (int t = 0; t < T_; t++) {
    const float* hprev = (t == 0) ? ss : hdec;
    Leg GH = { hprev, dec_U, dec_b + G3, g1, nullptr, 0, G3, H_, H_, G3, G3 };
    Leg GC = { ctx, dec_W + (size_t)D_ * G3, nullptr, g2, nullptr, 0, G3, H_, H_, G3, G3 };
    Leg GX;
    if (t == 0) {
      GX = { tgt_emb + 1 * D_ /*BOW=1*/, dec_W, dec_b, g0, nullptr, 0, G3, D_, 0, G3, G3 };
    } else {
      GX = { tgt_emb, dec_W, dec_b, g0, target_ids + (t - 1), T_, G3, D_, D_, G3, G3 };
    }
    gemm_legs<<<dim3(G3 / BN, B_ / BM, 3), 256, 0, stream>>>(GH, GC, GX, Z);
    dec_gate<<<(B_ * H_) / 256, 256, 0, stream>>>(g0, g2, g1, hprev, hdec);

    Leg LO = { hdec, out_W, out_b, out + (size_t)t * VT_, nullptr, 0, VT_, H_, H_, VT_, T_ * VT_ };
    Leg LP = { hdec, att_st_W, att_st_b, pbuf, nullptr, 0, H_, H_, H_, H_, H_ };
    gemm_legs<<<dim3(VT_ / BN, B_ / BM, 2), 256, 0, stream>>>(LO, LP, Z, Z);

    if (t < T_ - 1)
      attend_k<<<B_, 256, 0, stream>>>(proj, ss, pbuf, att_v, ctx);
  }
}